// Round 7
// baseline (53.506 us; speedup 1.0000x reference)
//
#include <hip/hip_runtime.h>
#include <math.h>

#define EPS 1e-6f
#define BN_EPSF 1e-5f
#define PI2F 6.2831853071795864769f
#define LOG2EF 1.4426950408889634f
#define NBB 4
#define NCC 512
#define NGG 2048
#define OUTC 64
#define NBAS 10

// d_out layout (floats): y_out, n_f, fourier_prior, n_h1, h0_f
#define Y_OFF   0
#define NF_OFF  (NBB*NGG*OUTC)          // 524288
#define FP_OFF  (NF_OFF  + NBB*NGG*9)   // 598016
#define NH1_OFF (FP_OFF  + NBB*NGG*9)   // 671744
#define H0_OFF  (NH1_OFF + NBB*NGG*9)   // 745472

// ws layout (floats)
#define WS_CONV  0                      // NBB*9*NGG = 73728
#define WS_STATS (NBB*9*NGG)            // 9 cps * 512 blocks * {sum,sumsq}

#if defined(__has_builtin)
# if __has_builtin(__builtin_amdgcn_exp2f)
#  define EXP2F(x) __builtin_amdgcn_exp2f(x)
# endif
#endif
#ifndef EXP2F
# define EXP2F(x) exp2f(x)
#endif

// ---------------------------------------------------------------------------
// K1: RBF sums (16 own g + 8 halo g) + Fourier prior + depthwise conv + BN
// partial stats. 512 blocks (4 b x 128 tiles of 16 g) x 512 threads.
// __launch_bounds__(512,4): 2 blocks/CU = 4 waves/SIMD, VGPR cap 128
// (round-6 lesson: 1024-thr block got capped at 64 VGPR -> 100 MB of spills).
// LDS ~31 KB via in-wave chunk folding so 2 blocks/CU fit.
// ---------------------------------------------------------------------------
__global__ __launch_bounds__(512, 4) void k1_rbf_conv(
    const float* __restrict__ x_c, const float* __restrict__ y_c,
    const float* __restrict__ x_g, const float* __restrict__ sigma,
    const float* __restrict__ mu, const float* __restrict__ eps1,
    const float* __restrict__ b_u, const float* __restrict__ random_w,
    const float* __restrict__ cw1, const float* __restrict__ cb1,
    const float* __restrict__ cw2, const float* __restrict__ cb2,
    const float* __restrict__ cw3, const float* __restrict__ cb3,
    float* __restrict__ out, float* __restrict__ ws)
{
    const int bid = blockIdx.x;
    const int b = bid >> 7;            // 4 b x 128 tiles
    const int gtile = bid & 127;
    const int g0 = gtile * 16;
    const int tid = threadIdx.x;

    __shared__ float4 cxy[NCC][2];     // 16 KB  (xc0,yc0,xc1,yc1),(xc2,yc2,-,-)
    __shared__ float red[8][16][18];   // 9.2 KB own-g per-wave partials
    __shared__ float red2[8][8][18];   // 4.6 KB halo per-wave partials
    __shared__ float pre_l[9][24];     // conv input: 0..3 left halo, 4..19 own, 20..23 right
    __shared__ float sw_l[NBAS*3], sb_l[NBAS*3], rw_l[NBAS];

    // ---- stage context set + small params ----
    const float* xcb = x_c + b*NCC*3;
    const float* ycb = y_c + b*NCC*3;
    float* cf = (float*)cxy;
    for (int i = tid; i < NCC*3; i += 512) {
        int n = i/3, c = i - n*3;
        cf[n*8 + 2*c]     = xcb[i];
        cf[n*8 + 2*c + 1] = ycb[i];
    }
    if (tid < NBAS*3) {
        int k = tid/3, p = tid - k*3;
        float wmu  = expf(mu[p]);
        float wstd = 1.0f / (expf(sigma[p]) + EPS);
        sw_l[tid] = wmu + wstd * eps1[(b*NBAS + k)*3 + p];
        sb_l[tid] = PI2F * b_u[(b*NBAS + k)*3 + p];
    }
    if (tid < NBAS) rw_l[tid] = random_w[tid];

    float coef[3];
    #pragma unroll
    for (int p = 0; p < 3; ++p) {
        float s = expf(sigma[p]) + EPS;
        coef[p] = (-0.5f * LOG2EF) / (s*s);   // exp(-0.5 d^2) == exp2(d^2*coef)
    }

    // ---- own-g mapping: g = tid&15, chunk cA = tid>>4 (32 chunks of 16 ctx) ----
    const int gA = tid & 15;
    const int cA = tid >> 4;
    float xgA0 = x_g[(b*NGG + g0 + gA)*3 + 0];
    float xgA1 = x_g[(b*NGG + g0 + gA)*3 + 1];
    float xgA2 = x_g[(b*NGG + g0 + gA)*3 + 2];

    // ---- halo mapping: gH = tid&7 (8 pts), cH = tid>>3 (64 chunks of 8 ctx) ----
    // halo slots in [g0-4, g0+20): offset 0..3 = left (g0-4..g0-1),
    // offset 20..23 = right (g0+16..g0+19).
    const int gH = tid & 7;
    const int cH = tid >> 3;
    const int gHg = g0 - 4 + ((gH < 4) ? gH : 20 + (gH - 4));  // global g of halo pt
    const int gHc = min(max(gHg, 0), NGG-1);                    // clamped for loads
    float xgH0 = x_g[(b*NGG + gHc)*3 + 0];
    float xgH1 = x_g[(b*NGG + gHc)*3 + 1];
    float xgH2 = x_g[(b*NGG + gHc)*3 + 2];

    __syncthreads();

    // ---- A1: own-g RBF (16 ctx per thread) ----
    float h0a[3][3] = {{0}}, h1a[3][3] = {{0}};
    const int nA0 = cA*16;
    for (int i = 0; i < 16; ++i) {
        float4 A = cxy[nA0 + i][0];
        float4 B = cxy[nA0 + i][1];
        float d0 = A.x - xgA0, d1 = A.z - xgA1, d2 = B.x - xgA2;
        float dx2[3] = {d0*d0, d1*d1, d2*d2};
        float yv[3]  = {A.y, A.w, B.y};
        #pragma unroll
        for (int c = 0; c < 3; ++c)
            #pragma unroll
            for (int p = 0; p < 3; ++p) {
                float w = EXP2F(dx2[c] * coef[p]);
                h0a[c][p] += w;
                h1a[c][p] += w * yv[c];
            }
    }
    // fold the wave's 4 chunks (lane bits 4,5 = cA low bits) in-register
    #pragma unroll
    for (int c = 0; c < 3; ++c)
        #pragma unroll
        for (int p = 0; p < 3; ++p) {
            #pragma unroll
            for (int m = 16; m <= 32; m <<= 1) {
                h0a[c][p] += __shfl_xor(h0a[c][p], m);
                h1a[c][p] += __shfl_xor(h1a[c][p], m);
            }
        }
    {
        int lane = tid & 63, wv = tid >> 6;
        if (lane < 16) {
            #pragma unroll
            for (int c = 0; c < 3; ++c)
                #pragma unroll
                for (int p = 0; p < 3; ++p) {
                    red[wv][gA][c*3 + p]     = h0a[c][p];
                    red[wv][gA][9 + c*3 + p] = h1a[c][p];
                }
        }
    }

    // ---- A2: halo RBF (8 ctx per thread, chunk-rotated -> 2-way banks) ----
    float h0b[3][3] = {{0}}, h1b[3][3] = {{0}};
    for (int i = 0; i < 8; ++i) {
        int n = cH*8 + ((i + cH) & 7);
        float4 A = cxy[n][0];
        float4 B = cxy[n][1];
        float d0 = A.x - xgH0, d1 = A.z - xgH1, d2 = B.x - xgH2;
        float dx2[3] = {d0*d0, d1*d1, d2*d2};
        float yv[3]  = {A.y, A.w, B.y};
        #pragma unroll
        for (int c = 0; c < 3; ++c)
            #pragma unroll
            for (int p = 0; p < 3; ++p) {
                float w = EXP2F(dx2[c] * coef[p]);
                h0b[c][p] += w;
                h1b[c][p] += w * yv[c];
            }
    }
    // in-wave reduce over the 8 chunks sharing gH (xor on lane bits 3/4/5)
    #pragma unroll
    for (int c = 0; c < 3; ++c)
        #pragma unroll
        for (int p = 0; p < 3; ++p) {
            #pragma unroll
            for (int m = 8; m <= 32; m <<= 1) {
                h0b[c][p] += __shfl_xor(h0b[c][p], m);
                h1b[c][p] += __shfl_xor(h1b[c][p], m);
            }
        }
    {
        int lane = tid & 63, wv = tid >> 6;
        if (lane < 8) {
            #pragma unroll
            for (int c = 0; c < 3; ++c)
                #pragma unroll
                for (int p = 0; p < 3; ++p) {
                    red2[wv][lane][c*3 + p]     = h0b[c][p];
                    red2[wv][lane][9 + c*3 + p] = h1b[c][p];
                }
        }
    }
    __syncthreads();

    // ---- finalize own g (144 items) and halo g (72 items) in parallel ----
    if (tid < 144) {
        int gl = tid / 9, cp = tid - gl*9;
        int c = cp / 3, p = cp - c*3;
        float h0 = 0.f, h1 = 0.f;
        #pragma unroll
        for (int q = 0; q < 8; ++q) {
            h0 += red[q][gl][cp];
            h1 += red[q][gl][9 + cp];
        }
        float nh1 = h1 / (h0 + EPS);
        float xg = x_g[(b*NGG + g0 + gl)*3 + c];
        float fp = 0.f;
        #pragma unroll
        for (int k = 0; k < NBAS; ++k) {
            // match numpy rounding: separate mul + add (no fma contraction)
            float arg = __fadd_rn(__fmul_rn(sw_l[k*3 + p], xg), sb_l[k*3 + p]);
            fp += rw_l[k] * cosf(arg);   // args reach ~4e4: keep accurate cosf
        }
        fp *= 0.44721359549995793f;      // sqrt(2/10)
        int base = (b*NGG + g0 + gl)*9 + cp;
        out[H0_OFF  + base] = h0;
        out[NH1_OFF + base] = nh1;
        out[FP_OFF  + base] = fp;
        pre_l[cp][4 + gl] = nh1 + fp;
    } else if (tid < 216) {
        int it = tid - 144;
        int gh = it / 9, cp = it - gh*9;
        int c = cp / 3, p = cp - c*3;
        float h0 = 0.f, h1 = 0.f;
        #pragma unroll
        for (int w = 0; w < 8; ++w) {
            h0 += red2[w][gh][cp];
            h1 += red2[w][gh][9 + cp];
        }
        int gg  = g0 - 4 + ((gh < 4) ? gh : 20 + (gh - 4));
        int idx = (gh < 4) ? gh : 20 + (gh - 4);
        bool valid = (gg >= 0) && (gg < NGG);
        int ggc = min(max(gg, 0), NGG-1);
        float nh1 = h1 / (h0 + EPS);
        float xg = x_g[(b*NGG + ggc)*3 + c];
        float fp = 0.f;
        #pragma unroll
        for (int k = 0; k < NBAS; ++k) {
            float arg = __fadd_rn(__fmul_rn(sw_l[k*3 + p], xg), sb_l[k*3 + p]);
            fp += rw_l[k] * cosf(arg);
        }
        fp *= 0.44721359549995793f;
        pre_l[cp][idx] = valid ? (nh1 + fp) : 0.f;   // zero-padding at grid edges
    }
    __syncthreads();

    // ---- depthwise conv (own 16 g) + deterministic BN partials ----
    float s1 = 0.f, s2 = 0.f;
    int cp2 = tid >> 4;            // valid when tid < 144: cp = tid/16
    if (tid < 144) {
        int gl = tid & 15;
        int c = cp2 / 3, p = cp2 - c*3;
        int K, pad; const float* w; float bias;
        if (p == 0)      { K = 3; pad = 1; w = cw1 + c*3; bias = cb1[c]; }
        else if (p == 1) { K = 5; pad = 2; w = cw2 + c*5; bias = cb2[c]; }
        else             { K = 9; pad = 4; w = cw3 + c*9; bias = cb3[c]; }
        float acc = bias;
        for (int k = 0; k < K; ++k)
            acc += w[k] * pre_l[cp2][4 + gl - pad + k];
        ws[WS_CONV + (b*9 + cp2)*NGG + g0 + gl] = acc;
        s1 = acc; s2 = acc*acc;
    }
    // reduce within each 16-lane group (same cp); masks <16 stay in-group
    #pragma unroll
    for (int m = 1; m <= 8; m <<= 1) {
        s1 += __shfl_xor(s1, m);
        s2 += __shfl_xor(s2, m);
    }
    if (tid < 144 && (tid & 15) == 0) {
        ws[WS_STATS + (cp2*512 + bid)*2]     = s1;
        ws[WS_STATS + (cp2*512 + bid)*2 + 1] = s2;
    }
}

// ---------------------------------------------------------------------------
// K2: BN stats reduce + normalize (n_f) + output GEMV. 2048 blocks x 256.
// ---------------------------------------------------------------------------
__global__ __launch_bounds__(256) void k2_out(
    const float* __restrict__ bn_gamma, const float* __restrict__ bn_beta,
    const float* __restrict__ g_w, const float* __restrict__ g_b,
    float* __restrict__ out, float* __restrict__ ws)
{
    __shared__ float gw_l[OUTC*18];
    __shared__ float feat_l[4][18];
    __shared__ float ps[9][16][2];
    __shared__ float mstat[9][2];
    const int tid = threadIdx.x;

    for (int i = tid; i < OUTC*18; i += 256) gw_l[i] = g_w[i];
    if (tid < 144) {
        int cp = tid / 16, q = tid & 15;
        float s1 = 0.f, s2 = 0.f;
        #pragma unroll 4
        for (int j = 0; j < 32; ++j) {
            int idx = WS_STATS + (cp*512 + q*32 + j)*2;
            s1 += ws[idx];
            s2 += ws[idx + 1];
        }
        ps[cp][q][0] = s1; ps[cp][q][1] = s2;
    }
    __syncthreads();
    if (tid < 9) {
        float s1 = 0.f, s2 = 0.f;
        #pragma unroll
        for (int q = 0; q < 16; ++q) { s1 += ps[tid][q][0]; s2 += ps[tid][q][1]; }
        float mean = s1 * (1.0f/8192.0f);
        float var  = s2 * (1.0f/8192.0f) - mean*mean;
        mstat[tid][0] = mean;
        mstat[tid][1] = rsqrtf(var + BN_EPSF);
    }
    __syncthreads();

    if (tid < 72) {
        int pt = tid / 18, j = tid - pt*18;
        int P = blockIdx.x*4 + pt;
        int b = P >> 11, g = P & 2047;
        float f;
        if (j < 9) {
            f = out[H0_OFF + (b*NGG + g)*9 + j];
        } else {
            int cp = j - 9; int c = cp / 3, p = cp - c*3;
            float x = ws[WS_CONV + (b*9 + cp)*NGG + g];
            float v = bn_gamma[p*3 + c] * (x - mstat[cp][0]) * mstat[cp][1]
                      + bn_beta[p*3 + c];
            out[NF_OFF + (b*NGG + g)*9 + cp] = v;
            f = v;
        }
        feat_l[pt][j] = f;
    }
    __syncthreads();

    int pt = tid >> 6, o = tid & 63;
    int P = blockIdx.x*4 + pt;
    int b = P >> 11, g = P & 2047;
    float acc = g_b[o];
    #pragma unroll
    for (int j = 0; j < 18; ++j) acc += feat_l[pt][j] * gw_l[o*18 + j];
    out[Y_OFF + (b*NGG + g)*OUTC + o] = acc;
}

extern "C" void kernel_launch(void* const* d_in, const int* in_sizes, int n_in,
                              void* d_out, int out_size, void* d_ws, size_t ws_size,
                              hipStream_t stream)
{
    const float* x_c      = (const float*)d_in[0];
    const float* y_c      = (const float*)d_in[1];
    const float* x_g      = (const float*)d_in[2];
    const float* sigma    = (const float*)d_in[3];
    const float* mu       = (const float*)d_in[4];
    const float* eps1     = (const float*)d_in[5];
    const float* b_u      = (const float*)d_in[6];
    const float* random_w = (const float*)d_in[7];
    const float* conv_w1  = (const float*)d_in[8];
    const float* conv_b1  = (const float*)d_in[9];
    const float* conv_w2  = (const float*)d_in[10];
    const float* conv_b2  = (const float*)d_in[11];
    const float* conv_w3  = (const float*)d_in[12];
    const float* conv_b3  = (const float*)d_in[13];
    const float* bn_gamma = (const float*)d_in[14];
    const float* bn_beta  = (const float*)d_in[15];
    const float* g_w      = (const float*)d_in[16];
    const float* g_b      = (const float*)d_in[17];

    float* outp = (float*)d_out;
    float* wsp  = (float*)d_ws;

    k1_rbf_conv<<<NBB*128, 512, 0, stream>>>(x_c, y_c, x_g, sigma, mu, eps1, b_u,
                                             random_w, conv_w1, conv_b1, conv_w2,
                                             conv_b2, conv_w3, conv_b3, outp, wsp);
    k2_out<<<(NBB*NGG)/4, 256, 0, stream>>>(bn_gamma, bn_beta, g_w, g_b, outp, wsp);
}

// Round 8
// 37.061 us; speedup vs baseline: 1.4437x; 1.4437x over previous
//
#include <hip/hip_runtime.h>
#include <math.h>

#define EPS 1e-6f
#define BN_EPSF 1e-5f
#define PI2F 6.2831853071795864769f
#define LOG2EF 1.4426950408889634f
#define NBB 4
#define NCC 512
#define NGG 2048
#define OUTC 64
#define NBAS 10

// d_out layout (floats): y_out, n_f, fourier_prior, n_h1, h0_f
#define Y_OFF   0
#define NF_OFF  (NBB*NGG*OUTC)          // 524288
#define FP_OFF  (NF_OFF  + NBB*NGG*9)   // 598016
#define NH1_OFF (FP_OFF  + NBB*NGG*9)   // 671744
#define H0_OFF  (NH1_OFF + NBB*NGG*9)   // 745472

// ws layout (floats)
#define WS_CONV  0                      // NBB*9*NGG = 73728
#define WS_STATS (NBB*9*NGG)            // 9 cps * 512 blocks * {sum,sumsq}

#if defined(__has_builtin)
# if __has_builtin(__builtin_amdgcn_exp2f)
#  define EXP2F(x) __builtin_amdgcn_exp2f(x)
# endif
#endif
#ifndef EXP2F
# define EXP2F(x) exp2f(x)
#endif

// ---------------------------------------------------------------------------
// K1: RBF sums (16 own g + 8 halo g) + Fourier prior + depthwise conv + BN
// partial stats. 512 blocks (4 b x 128 tiles of 16 g) x 256 threads.
//
// Register discipline (rounds 6/7 lesson: compiler capped VGPR at 64 and
// spilled ~100 MB of accumulators to scratch): p-loop is OUTSIDE the context
// loop, so only 6 accumulators (3 ch x {h0,h1}) are live at a time. 256-thr
// block (4 waves) imposes no residency-driven VGPR cap.
// ---------------------------------------------------------------------------
__global__ __launch_bounds__(256) void k1_rbf_conv(
    const float* __restrict__ x_c, const float* __restrict__ y_c,
    const float* __restrict__ x_g, const float* __restrict__ sigma,
    const float* __restrict__ mu, const float* __restrict__ eps1,
    const float* __restrict__ b_u, const float* __restrict__ random_w,
    const float* __restrict__ cw1, const float* __restrict__ cb1,
    const float* __restrict__ cw2, const float* __restrict__ cb2,
    const float* __restrict__ cw3, const float* __restrict__ cb3,
    float* __restrict__ out, float* __restrict__ ws)
{
    const int bid = blockIdx.x;
    const int b = bid >> 7;            // 4 b x 128 tiles
    const int gtile = bid & 127;
    const int g0 = gtile * 16;
    const int tid = threadIdx.x;

    __shared__ float4 cxy[NCC][2];     // 16 KB  (xc0,yc0,xc1,yc1),(xc2,yc2,-,-)
    __shared__ float red[4][16][18];   // 4.6 KB own-g per-wave partials
    __shared__ float red2[4][8][18];   // 2.3 KB halo per-wave partials
    __shared__ float pre_l[9][24];     // conv input: 0..3 left halo, 4..19 own, 20..23 right
    __shared__ float sw_l[NBAS*3], sb_l[NBAS*3], rw_l[NBAS];

    // ---- stage context set + small params ----
    const float* xcb = x_c + b*NCC*3;
    const float* ycb = y_c + b*NCC*3;
    float* cf = (float*)cxy;
    for (int i = tid; i < NCC*3; i += 256) {
        int n = i/3, c = i - n*3;
        cf[n*8 + 2*c]     = xcb[i];
        cf[n*8 + 2*c + 1] = ycb[i];
    }
    if (tid < NBAS*3) {
        int k = tid/3, p = tid - k*3;
        float wmu  = expf(mu[p]);
        float wstd = 1.0f / (expf(sigma[p]) + EPS);
        sw_l[tid] = wmu + wstd * eps1[(b*NBAS + k)*3 + p];
        sb_l[tid] = PI2F * b_u[(b*NBAS + k)*3 + p];
    }
    if (tid < NBAS) rw_l[tid] = random_w[tid];

    float coef[3];
    #pragma unroll
    for (int p = 0; p < 3; ++p) {
        float s = expf(sigma[p]) + EPS;
        coef[p] = (-0.5f * LOG2EF) / (s*s);   // exp(-0.5 d^2) == exp2(d^2*coef)
    }

    // ---- own-g mapping: g = tid&15, chunk cA = tid>>4 (16 chunks of 32 ctx) ----
    const int gA = tid & 15;
    const int cA = tid >> 4;
    const float xgA0 = x_g[(b*NGG + g0 + gA)*3 + 0];
    const float xgA1 = x_g[(b*NGG + g0 + gA)*3 + 1];
    const float xgA2 = x_g[(b*NGG + g0 + gA)*3 + 2];

    // ---- halo mapping: gH = tid&7 (8 pts), cH = tid>>3 (32 chunks of 16 ctx) ----
    // halo slots in [g0-4, g0+20): offset 0..3 = left (g0-4..g0-1),
    // offset 20..23 = right (g0+16..g0+19).
    const int gH = tid & 7;
    const int cH = tid >> 3;
    const int gHg = g0 - 4 + ((gH < 4) ? gH : 20 + (gH - 4));  // global g of halo pt
    const int gHc = min(max(gHg, 0), NGG-1);                    // clamped for loads
    const float xgH0 = x_g[(b*NGG + gHc)*3 + 0];
    const float xgH1 = x_g[(b*NGG + gHc)*3 + 1];
    const float xgH2 = x_g[(b*NGG + gHc)*3 + 2];

    __syncthreads();

    const int lane = tid & 63, wv = tid >> 6;

    // ---- A1: own-g RBF, p outermost (6 live accumulators per pass) ----
    // wave has 4 chunk-groups (cA low 2 bits = lane bits 4,5); rotation
    // (i + cA)&31 spreads the 4 broadcast groups over 4 LDS bank-groups.
    const int nA0 = cA * 32;
    #pragma unroll
    for (int p = 0; p < 3; ++p) {
        const float cpf = coef[p];
        float h00 = 0.f, h01 = 0.f, h02 = 0.f;
        float h10 = 0.f, h11 = 0.f, h12 = 0.f;
        for (int i = 0; i < 32; ++i) {
            int n = nA0 + ((i + cA) & 31);
            float4 A = cxy[n][0];
            float4 B = cxy[n][1];
            float d0 = A.x - xgA0, d1 = A.z - xgA1, d2 = B.x - xgA2;
            float w0 = EXP2F(d0*d0 * cpf);
            float w1 = EXP2F(d1*d1 * cpf);
            float w2 = EXP2F(d2*d2 * cpf);
            h00 += w0; h10 += w0 * A.y;
            h01 += w1; h11 += w1 * A.w;
            h02 += w2; h12 += w2 * B.y;
        }
        // fold the wave's 4 chunks (lane bits 4,5)
        #pragma unroll
        for (int m = 16; m <= 32; m <<= 1) {
            h00 += __shfl_xor(h00, m); h10 += __shfl_xor(h10, m);
            h01 += __shfl_xor(h01, m); h11 += __shfl_xor(h11, m);
            h02 += __shfl_xor(h02, m); h12 += __shfl_xor(h12, m);
        }
        if (lane < 16) {
            red[wv][gA][0*3 + p] = h00;  red[wv][gA][9 + 0*3 + p] = h10;
            red[wv][gA][1*3 + p] = h01;  red[wv][gA][9 + 1*3 + p] = h11;
            red[wv][gA][2*3 + p] = h02;  red[wv][gA][9 + 2*3 + p] = h12;
        }
    }

    // ---- A2: halo RBF, p outermost; 8 chunk-groups/wave, rotated ----
    const int nH0 = cH * 16;
    #pragma unroll
    for (int p = 0; p < 3; ++p) {
        const float cpf = coef[p];
        float h00 = 0.f, h01 = 0.f, h02 = 0.f;
        float h10 = 0.f, h11 = 0.f, h12 = 0.f;
        for (int i = 0; i < 16; ++i) {
            int n = nH0 + ((i + cH) & 15);
            float4 A = cxy[n][0];
            float4 B = cxy[n][1];
            float d0 = A.x - xgH0, d1 = A.z - xgH1, d2 = B.x - xgH2;
            float w0 = EXP2F(d0*d0 * cpf);
            float w1 = EXP2F(d1*d1 * cpf);
            float w2 = EXP2F(d2*d2 * cpf);
            h00 += w0; h10 += w0 * A.y;
            h01 += w1; h11 += w1 * A.w;
            h02 += w2; h12 += w2 * B.y;
        }
        // fold the wave's 8 chunks (lane bits 3,4,5)
        #pragma unroll
        for (int m = 8; m <= 32; m <<= 1) {
            h00 += __shfl_xor(h00, m); h10 += __shfl_xor(h10, m);
            h01 += __shfl_xor(h01, m); h11 += __shfl_xor(h11, m);
            h02 += __shfl_xor(h02, m); h12 += __shfl_xor(h12, m);
        }
        if (lane < 8) {
            red2[wv][gH][0*3 + p] = h00;  red2[wv][gH][9 + 0*3 + p] = h10;
            red2[wv][gH][1*3 + p] = h01;  red2[wv][gH][9 + 1*3 + p] = h11;
            red2[wv][gH][2*3 + p] = h02;  red2[wv][gH][9 + 2*3 + p] = h12;
        }
    }
    __syncthreads();

    // ---- finalize own g (144 items) and halo g (72 items) in parallel ----
    if (tid < 144) {
        int gl = tid / 9, cp = tid - gl*9;
        int c = cp / 3, p = cp - c*3;
        float h0 = 0.f, h1 = 0.f;
        #pragma unroll
        for (int q = 0; q < 4; ++q) {
            h0 += red[q][gl][cp];
            h1 += red[q][gl][9 + cp];
        }
        float nh1 = h1 / (h0 + EPS);
        float xg = x_g[(b*NGG + g0 + gl)*3 + c];
        float fp = 0.f;
        #pragma unroll
        for (int k = 0; k < NBAS; ++k) {
            // match numpy rounding: separate mul + add (no fma contraction)
            float arg = __fadd_rn(__fmul_rn(sw_l[k*3 + p], xg), sb_l[k*3 + p]);
            fp += rw_l[k] * cosf(arg);   // args reach ~4e4: keep accurate cosf
        }
        fp *= 0.44721359549995793f;      // sqrt(2/10)
        int base = (b*NGG + g0 + gl)*9 + cp;
        out[H0_OFF  + base] = h0;
        out[NH1_OFF + base] = nh1;
        out[FP_OFF  + base] = fp;
        pre_l[cp][4 + gl] = nh1 + fp;
    } else if (tid < 216) {
        int it = tid - 144;
        int gh = it / 9, cp = it - gh*9;
        int c = cp / 3, p = cp - c*3;
        float h0 = 0.f, h1 = 0.f;
        #pragma unroll
        for (int q = 0; q < 4; ++q) {
            h0 += red2[q][gh][cp];
            h1 += red2[q][gh][9 + cp];
        }
        int gg  = g0 - 4 + ((gh < 4) ? gh : 20 + (gh - 4));
        int idx = (gh < 4) ? gh : 20 + (gh - 4);
        bool valid = (gg >= 0) && (gg < NGG);
        int ggc = min(max(gg, 0), NGG-1);
        float nh1 = h1 / (h0 + EPS);
        float xg = x_g[(b*NGG + ggc)*3 + c];
        float fp = 0.f;
        #pragma unroll
        for (int k = 0; k < NBAS; ++k) {
            float arg = __fadd_rn(__fmul_rn(sw_l[k*3 + p], xg), sb_l[k*3 + p]);
            fp += rw_l[k] * cosf(arg);
        }
        fp *= 0.44721359549995793f;
        pre_l[cp][idx] = valid ? (nh1 + fp) : 0.f;   // zero-padding at grid edges
    }
    __syncthreads();

    // ---- depthwise conv (own 16 g) + deterministic BN partials ----
    float s1 = 0.f, s2 = 0.f;
    int cp2 = tid >> 4;            // valid when tid < 144: cp = tid/16
    if (tid < 144) {
        int gl = tid & 15;
        int c = cp2 / 3, p = cp2 - c*3;
        int K, pad; const float* w; float bias;
        if (p == 0)      { K = 3; pad = 1; w = cw1 + c*3; bias = cb1[c]; }
        else if (p == 1) { K = 5; pad = 2; w = cw2 + c*5; bias = cb2[c]; }
        else             { K = 9; pad = 4; w = cw3 + c*9; bias = cb3[c]; }
        float acc = bias;
        for (int k = 0; k < K; ++k)
            acc += w[k] * pre_l[cp2][4 + gl - pad + k];
        ws[WS_CONV + (b*9 + cp2)*NGG + g0 + gl] = acc;
        s1 = acc; s2 = acc*acc;
    }
    // reduce within each 16-lane group (same cp); masks <16 stay in-group
    #pragma unroll
    for (int m = 1; m <= 8; m <<= 1) {
        s1 += __shfl_xor(s1, m);
        s2 += __shfl_xor(s2, m);
    }
    if (tid < 144 && (tid & 15) == 0) {
        ws[WS_STATS + (cp2*512 + bid)*2]     = s1;
        ws[WS_STATS + (cp2*512 + bid)*2 + 1] = s2;
    }
}

// ---------------------------------------------------------------------------
// K2: BN stats reduce + normalize (n_f) + output GEMV. 2048 blocks x 256.
// ---------------------------------------------------------------------------
__global__ __launch_bounds__(256) void k2_out(
    const float* __restrict__ bn_gamma, const float* __restrict__ bn_beta,
    const float* __restrict__ g_w, const float* __restrict__ g_b,
    float* __restrict__ out, float* __restrict__ ws)
{
    __shared__ float gw_l[OUTC*18];
    __shared__ float feat_l[4][18];
    __shared__ float ps[9][16][2];
    __shared__ float mstat[9][2];
    const int tid = threadIdx.x;

    for (int i = tid; i < OUTC*18; i += 256) gw_l[i] = g_w[i];
    if (tid < 144) {
        int cp = tid / 16, q = tid & 15;
        float s1 = 0.f, s2 = 0.f;
        #pragma unroll 4
        for (int j = 0; j < 32; ++j) {
            int idx = WS_STATS + (cp*512 + q*32 + j)*2;
            s1 += ws[idx];
            s2 += ws[idx + 1];
        }
        ps[cp][q][0] = s1; ps[cp][q][1] = s2;
    }
    __syncthreads();
    if (tid < 9) {
        float s1 = 0.f, s2 = 0.f;
        #pragma unroll
        for (int q = 0; q < 16; ++q) { s1 += ps[tid][q][0]; s2 += ps[tid][q][1]; }
        float mean = s1 * (1.0f/8192.0f);
        float var  = s2 * (1.0f/8192.0f) - mean*mean;
        mstat[tid][0] = mean;
        mstat[tid][1] = rsqrtf(var + BN_EPSF);
    }
    __syncthreads();

    if (tid < 72) {
        int pt = tid / 18, j = tid - pt*18;
        int P = blockIdx.x*4 + pt;
        int b = P >> 11, g = P & 2047;
        float f;
        if (j < 9) {
            f = out[H0_OFF + (b*NGG + g)*9 + j];
        } else {
            int cp = j - 9; int c = cp / 3, p = cp - c*3;
            float x = ws[WS_CONV + (b*9 + cp)*NGG + g];
            float v = bn_gamma[p*3 + c] * (x - mstat[cp][0]) * mstat[cp][1]
                      + bn_beta[p*3 + c];
            out[NF_OFF + (b*NGG + g)*9 + cp] = v;
            f = v;
        }
        feat_l[pt][j] = f;
    }
    __syncthreads();

    int pt = tid >> 6, o = tid & 63;
    int P = blockIdx.x*4 + pt;
    int b = P >> 11, g = P & 2047;
    float acc = g_b[o];
    #pragma unroll
    for (int j = 0; j < 18; ++j) acc += feat_l[pt][j] * gw_l[o*18 + j];
    out[Y_OFF + (b*NGG + g)*OUTC + o] = acc;
}

extern "C" void kernel_launch(void* const* d_in, const int* in_sizes, int n_in,
                              void* d_out, int out_size, void* d_ws, size_t ws_size,
                              hipStream_t stream)
{
    const float* x_c      = (const float*)d_in[0];
    const float* y_c      = (const float*)d_in[1];
    const float* x_g      = (const float*)d_in[2];
    const float* sigma    = (const float*)d_in[3];
    const float* mu       = (const float*)d_in[4];
    const float* eps1     = (const float*)d_in[5];
    const float* b_u      = (const float*)d_in[6];
    const float* random_w = (const float*)d_in[7];
    const float* conv_w1  = (const float*)d_in[8];
    const float* conv_b1  = (const float*)d_in[9];
    const float* conv_w2  = (const float*)d_in[10];
    const float* conv_b2  = (const float*)d_in[11];
    const float* conv_w3  = (const float*)d_in[12];
    const float* conv_b3  = (const float*)d_in[13];
    const float* bn_gamma = (const float*)d_in[14];
    const float* bn_beta  = (const float*)d_in[15];
    const float* g_w      = (const float*)d_in[16];
    const float* g_b      = (const float*)d_in[17];

    float* outp = (float*)d_out;
    float* wsp  = (float*)d_ws;

    k1_rbf_conv<<<NBB*128, 256, 0, stream>>>(x_c, y_c, x_g, sigma, mu, eps1, b_u,
                                             random_w, conv_w1, conv_b1, conv_w2,
                                             conv_b2, conv_w3, conv_b3, outp, wsp);
    k2_out<<<(NBB*NGG)/4, 256, 0, stream>>>(bn_gamma, bn_beta, g_w, g_b, outp, wsp);
}

// Round 9
// 24.339 us; speedup vs baseline: 2.1983x; 1.5227x over previous
//
#include <hip/hip_runtime.h>
#include <math.h>

#define EPS 1e-6f
#define BN_EPSF 1e-5f
#define PI2F 6.2831853071795864769f
#define LOG2EF 1.4426950408889634f
#define NBB 4
#define NCC 512
#define NGG 2048
#define OUTC 64
#define NBAS 10

// d_out layout (floats): y_out, n_f, fourier_prior, n_h1, h0_f
#define Y_OFF   0
#define NF_OFF  (NBB*NGG*OUTC)          // 524288
#define FP_OFF  (NF_OFF  + NBB*NGG*9)   // 598016
#define NH1_OFF (FP_OFF  + NBB*NGG*9)   // 671744
#define H0_OFF  (NH1_OFF + NBB*NGG*9)   // 745472

// ws layout (floats)
#define WS_PRE   0                      // NBB*9*NGG = 73728
#define WS_CONV  (NBB*9*NGG)            // 73728
#define WS_STATS (2*NBB*9*NGG)          // 9 cps * 32 blocks * {sum,sumsq}

#if defined(__has_builtin)
# if __has_builtin(__builtin_amdgcn_exp2f)
#  define EXP2F(x) __builtin_amdgcn_exp2f(x)
# endif
#endif
#ifndef EXP2F
# define EXP2F(x) exp2f(x)
#endif

// ---------------------------------------------------------------------------
// K1: RBF sums + Fourier prior for 16 own g (NO halo — conv is a separate
// kernel, so exp count is the 37.7M minimum). 512 blocks (4 b x 128 tiles)
// x 256 threads = 2 blocks/CU = 2 waves/SIMD.
// p-inner: 18 accumulators live (proven non-spilling at 256 thr in rounds
// 1-2; rounds 6-8 lesson: p-outer avoids spills but 3x the LDS reads/iters).
// Chunk partials -> padded LDS red[16][16][19] directly; no shuffle folds.
// ---------------------------------------------------------------------------
__global__ __launch_bounds__(256) void k1_rbf(
    const float* __restrict__ x_c, const float* __restrict__ y_c,
    const float* __restrict__ x_g, const float* __restrict__ sigma,
    const float* __restrict__ mu, const float* __restrict__ eps1,
    const float* __restrict__ b_u, const float* __restrict__ random_w,
    float* __restrict__ out, float* __restrict__ ws)
{
    const int bid = blockIdx.x;
    const int b = bid >> 7;            // 4 b x 128 tiles of 16 g
    const int gtile = bid & 127;
    const int g0 = gtile * 16;
    const int tid = threadIdx.x;

    __shared__ float4 cxy[NCC][2];     // 16 KB (xc0,yc0,xc1,yc1),(xc2,yc2,-,-)
    __shared__ float red[16][16][19];  // 19.5 KB chunk partials, +1 pad (<=2-way banks)
    __shared__ float sw_l[NBAS*3], sb_l[NBAS*3], rw_l[NBAS];

    // ---- stage context set + small params ----
    const float* xcb = x_c + b*NCC*3;
    const float* ycb = y_c + b*NCC*3;
    float* cf = (float*)cxy;
    for (int i = tid; i < NCC*3; i += 256) {
        int n = i/3, c = i - n*3;
        cf[n*8 + 2*c]     = xcb[i];
        cf[n*8 + 2*c + 1] = ycb[i];
    }
    if (tid < NBAS*3) {
        int k = tid/3, p = tid - k*3;
        float wmu  = expf(mu[p]);
        float wstd = 1.0f / (expf(sigma[p]) + EPS);
        sw_l[tid] = wmu + wstd * eps1[(b*NBAS + k)*3 + p];
        sb_l[tid] = PI2F * b_u[(b*NBAS + k)*3 + p];
    }
    if (tid < NBAS) rw_l[tid] = random_w[tid];

    float coef[3];
    #pragma unroll
    for (int p = 0; p < 3; ++p) {
        float s = expf(sigma[p]) + EPS;
        coef[p] = (-0.5f * LOG2EF) / (s*s);   // exp(-0.5 d^2) == exp2(d^2*coef)
    }

    // ---- mapping: g = tid&15, chunk cA = tid>>4 (16 chunks of 32 ctx) ----
    const int gA = tid & 15;
    const int cA = tid >> 4;
    const float xg0 = x_g[(b*NGG + g0 + gA)*3 + 0];
    const float xg1 = x_g[(b*NGG + g0 + gA)*3 + 1];
    const float xg2 = x_g[(b*NGG + g0 + gA)*3 + 2];

    __syncthreads();

    // ---- RBF inner loop: single pass over 32 ctx, 9 exp per iter ----
    // rotation (i+cA)&31: the wave's 4 cA-groups hit 4 distinct bank-quads
    // (n%4 distinct) -> conflict-free 4-address broadcast reads.
    float h0a[3][3] = {{0}}, h1a[3][3] = {{0}};
    const int nA0 = cA * 32;
    for (int i = 0; i < 32; ++i) {
        int n = nA0 + ((i + cA) & 31);
        float4 A = cxy[n][0];
        float4 B = cxy[n][1];
        float d0 = A.x - xg0, d1 = A.z - xg1, d2 = B.x - xg2;
        float dx2[3] = {d0*d0, d1*d1, d2*d2};
        float yv[3]  = {A.y, A.w, B.y};
        #pragma unroll
        for (int c = 0; c < 3; ++c)
            #pragma unroll
            for (int p = 0; p < 3; ++p) {
                float w = EXP2F(dx2[c] * coef[p]);
                h0a[c][p] += w;
                h1a[c][p] += w * yv[c];
            }
    }
    #pragma unroll
    for (int c = 0; c < 3; ++c)
        #pragma unroll
        for (int p = 0; p < 3; ++p) {
            red[cA][gA][c*3 + p]     = h0a[c][p];
            red[cA][gA][9 + c*3 + p] = h1a[c][p];
        }
    __syncthreads();

    // ---- finalize 16*9 = 144 outputs: reduce 16 chunks + Fourier prior ----
    if (tid < 144) {
        int gl = tid / 9, cp = tid - gl*9;
        int c = cp / 3, p = cp - c*3;
        float h0 = 0.f, h1 = 0.f;
        #pragma unroll
        for (int q = 0; q < 16; ++q) {
            h0 += red[q][gl][cp];
            h1 += red[q][gl][9 + cp];
        }
        float nh1 = h1 / (h0 + EPS);
        float xg = x_g[(b*NGG + g0 + gl)*3 + c];
        float fp = 0.f;
        #pragma unroll
        for (int k = 0; k < NBAS; ++k) {
            // match numpy rounding: separate mul + add (no fma contraction)
            float arg = __fadd_rn(__fmul_rn(sw_l[k*3 + p], xg), sb_l[k*3 + p]);
            fp += rw_l[k] * cosf(arg);   // args reach ~4e4: keep accurate cosf
        }
        fp *= 0.44721359549995793f;      // sqrt(2/10)
        int base = (b*NGG + g0 + gl)*9 + cp;
        out[H0_OFF  + base] = h0;
        out[NH1_OFF + base] = nh1;
        out[FP_OFF  + base] = fp;
        ws[WS_PRE + (b*9 + cp)*NGG + g0 + gl] = nh1 + fp;
    }
}

// ---------------------------------------------------------------------------
// K2: depthwise conv along g + deterministic BN partial stats.
// 288 blocks (4 b x 9 cp x 8 g-chunks) x 256 threads. Reads pre from ws
// (global) -> no halo recompute anywhere.
// ---------------------------------------------------------------------------
__global__ __launch_bounds__(256) void k2_conv(
    const float* __restrict__ cw1, const float* __restrict__ cb1,
    const float* __restrict__ cw2, const float* __restrict__ cb2,
    const float* __restrict__ cw3, const float* __restrict__ cb3,
    float* __restrict__ ws)
{
    int bid = blockIdx.x;                 // nb*9*8 = 288
    int b = bid / 72; int r = bid - b*72;
    int cp = r / 8;  int gc = r - cp*8;
    int g = gc*256 + threadIdx.x;
    int c = cp / 3, p = cp - c*3;
    const float* pre = ws + WS_PRE + (b*9 + cp)*NGG;

    int K, pad; const float* w; float bias;
    if (p == 0)      { K = 3; pad = 1; w = cw1 + c*3; bias = cb1[c]; }
    else if (p == 1) { K = 5; pad = 2; w = cw2 + c*5; bias = cb2[c]; }
    else             { K = 9; pad = 4; w = cw3 + c*9; bias = cb3[c]; }

    float acc = bias;
    for (int k = 0; k < K; ++k) {
        int idx = g - pad + k;
        if (idx >= 0 && idx < NGG) acc += w[k] * pre[idx];
    }
    ws[WS_CONV + (b*9 + cp)*NGG + g] = acc;

    // BN stats: block reduce -> deterministic per-block partial (no atomics)
    float s1 = acc, s2 = acc*acc;
    #pragma unroll
    for (int o = 32; o > 0; o >>= 1) {
        s1 += __shfl_down(s1, o);
        s2 += __shfl_down(s2, o);
    }
    __shared__ float r1[4], r2[4];
    int lane = threadIdx.x & 63, wv = threadIdx.x >> 6;
    if (lane == 0) { r1[wv] = s1; r2[wv] = s2; }
    __syncthreads();
    if (threadIdx.x == 0) {
        float t1 = r1[0] + r1[1] + r1[2] + r1[3];
        float t2 = r2[0] + r2[1] + r2[2] + r2[3];
        int pidx = cp*32 + b*8 + gc;
        ws[WS_STATS + pidx*2]     = t1;
        ws[WS_STATS + pidx*2 + 1] = t2;
    }
}

// ---------------------------------------------------------------------------
// K3: BN stats reduce + normalize (n_f) + output GEMV. 2048 blocks x 256.
// ---------------------------------------------------------------------------
__global__ __launch_bounds__(256) void k3_out(
    const float* __restrict__ bn_gamma, const float* __restrict__ bn_beta,
    const float* __restrict__ g_w, const float* __restrict__ g_b,
    float* __restrict__ out, float* __restrict__ ws)
{
    __shared__ float gw_l[OUTC*18];
    __shared__ float feat_l[4][18];
    __shared__ float ps[9][16][2];
    __shared__ float mstat[9][2];
    const int tid = threadIdx.x;

    for (int i = tid; i < OUTC*18; i += 256) gw_l[i] = g_w[i];
    if (tid < 144) {
        int cp = tid / 16, q = tid & 15;
        int idx = WS_STATS + (cp*32 + 2*q)*2;
        ps[cp][q][0] = ws[idx]     + ws[idx + 2];
        ps[cp][q][1] = ws[idx + 1] + ws[idx + 3];
    }
    __syncthreads();
    if (tid < 9) {
        float s1 = 0.f, s2 = 0.f;
        #pragma unroll
        for (int q = 0; q < 16; ++q) { s1 += ps[tid][q][0]; s2 += ps[tid][q][1]; }
        float mean = s1 * (1.0f/8192.0f);
        float var  = s2 * (1.0f/8192.0f) - mean*mean;
        mstat[tid][0] = mean;
        mstat[tid][1] = rsqrtf(var + BN_EPSF);
    }
    __syncthreads();

    if (tid < 72) {
        int pt = tid / 18, j = tid - pt*18;
        int P = blockIdx.x*4 + pt;
        int b = P >> 11, g = P & 2047;
        float f;
        if (j < 9) {
            f = out[H0_OFF + (b*NGG + g)*9 + j];
        } else {
            int cp = j - 9; int c = cp / 3, p = cp - c*3;
            float x = ws[WS_CONV + (b*9 + cp)*NGG + g];
            float v = bn_gamma[p*3 + c] * (x - mstat[cp][0]) * mstat[cp][1]
                      + bn_beta[p*3 + c];
            out[NF_OFF + (b*NGG + g)*9 + cp] = v;
            f = v;
        }
        feat_l[pt][j] = f;
    }
    __syncthreads();

    int pt = tid >> 6, o = tid & 63;
    int P = blockIdx.x*4 + pt;
    int b = P >> 11, g = P & 2047;
    float acc = g_b[o];
    #pragma unroll
    for (int j = 0; j < 18; ++j) acc += feat_l[pt][j] * gw_l[o*18 + j];
    out[Y_OFF + (b*NGG + g)*OUTC + o] = acc;
}

extern "C" void kernel_launch(void* const* d_in, const int* in_sizes, int n_in,
                              void* d_out, int out_size, void* d_ws, size_t ws_size,
                              hipStream_t stream)
{
    const float* x_c      = (const float*)d_in[0];
    const float* y_c      = (const float*)d_in[1];
    const float* x_g      = (const float*)d_in[2];
    const float* sigma    = (const float*)d_in[3];
    const float* mu       = (const float*)d_in[4];
    const float* eps1     = (const float*)d_in[5];
    const float* b_u      = (const float*)d_in[6];
    const float* random_w = (const float*)d_in[7];
    const float* conv_w1  = (const float*)d_in[8];
    const float* conv_b1  = (const float*)d_in[9];
    const float* conv_w2  = (const float*)d_in[10];
    const float* conv_b2  = (const float*)d_in[11];
    const float* conv_w3  = (const float*)d_in[12];
    const float* conv_b3  = (const float*)d_in[13];
    const float* bn_gamma = (const float*)d_in[14];
    const float* bn_beta  = (const float*)d_in[15];
    const float* g_w      = (const float*)d_in[16];
    const float* g_b      = (const float*)d_in[17];

    float* outp = (float*)d_out;
    float* wsp  = (float*)d_ws;

    k1_rbf<<<NBB*128, 256, 0, stream>>>(x_c, y_c, x_g, sigma, mu, eps1, b_u,
                                        random_w, outp, wsp);
    k2_conv<<<NBB*9*(NGG/256), 256, 0, stream>>>(conv_w1, conv_b1, conv_w2, conv_b2,
                                                 conv_w3, conv_b3, wsp);
    k3_out<<<(NBB*NGG)/4, 256, 0, stream>>>(bn_gamma, bn_beta, g_w, g_b, outp, wsp);
}